// Round 5
// baseline (314.851 us; speedup 1.0000x reference)
//
#include <hip/hip_runtime.h>
#include <hip/hip_bf16.h>

typedef _Float16 half8 __attribute__((ext_vector_type(8)));
typedef float floatx4 __attribute__((ext_vector_type(4)));

#define MFMA16H(a, b, c) __builtin_amdgcn_mfma_f32_16x16x32_f16((a), (b), (c), 0, 0, 0)

static constexpr int Bb = 8, Nn = 2048, Mm = 2048, Dd = 256;

// async global->LDS DMA, 16B per lane. LDS dest = wave-uniform base + lane*16.
__device__ inline void async16(const void* g, void* l)
{
    __builtin_amdgcn_global_load_lds((const __attribute__((address_space(1))) unsigned int*)g,
                                     (__attribute__((address_space(3))) unsigned int*)l,
                                     16, 0, 0);
}

// Load 8 consecutive fp32, round to fp16.
__device__ inline half8 cvt8h(const float* __restrict__ p)
{
    float4 f0 = *reinterpret_cast<const float4*>(p);
    float4 f1 = *reinterpret_cast<const float4*>(p + 4);
    half8 r;
    r[0] = (_Float16)f0.x; r[1] = (_Float16)f0.y; r[2] = (_Float16)f0.z; r[3] = (_Float16)f0.w;
    r[4] = (_Float16)f1.x; r[5] = (_Float16)f1.y; r[6] = (_Float16)f1.z; r[7] = (_Float16)f1.w;
    return r;
}

// hi/lo fp16 split: x = hi + lo.
__device__ inline void cvt8h_split(const float* __restrict__ p, half8& h, half8& l)
{
    float4 f0 = *reinterpret_cast<const float4*>(p);
    float4 f1 = *reinterpret_cast<const float4*>(p + 4);
    float f[8] = {f0.x, f0.y, f0.z, f0.w, f1.x, f1.y, f1.z, f1.w};
#pragma unroll
    for (int i = 0; i < 8; ++i) {
        _Float16 hh = (_Float16)f[i];
        h[i] = hh;
        l[i] = (_Float16)(f[i] - (float)hh);
    }
}

// ---------------------------------------------------------------------------
// Kernel 1 (prep): blocks [0,1024): FiH fp16 + FiT fp16 transpose.
//                  blocks [1024,1056): W -> Wh/Wl fp16 split.
// ---------------------------------------------------------------------------
__global__ __launch_bounds__(256, 4)
void prep_kernel(const float* __restrict__ Fi, const float* __restrict__ W,
                 _Float16* __restrict__ FiH, _Float16* __restrict__ FiT,
                 _Float16* __restrict__ Wh, _Float16* __restrict__ Wl)
{
    const int bid = blockIdx.x;
    const int t = threadIdx.x;

    if (bid >= 1024) {
        const size_t base = (size_t)(bid - 1024) * 2048 + t * 8;
        half8 h, l;
        cvt8h_split(W + base, h, l);
        *(half8*)(Wh + base) = h;
        *(half8*)(Wl + base) = l;
        return;
    }

    __shared__ __align__(16) unsigned short tile[64][72];  // +8 pad
    const int b  = bid >> 7;
    const int mt = (bid >> 2) & 31;
    const int dt = bid & 3;

    {
        const int i = t >> 2, jc = (t & 3) * 16;
        const float* src = Fi + ((size_t)b * Mm + mt * 64 + i) * Dd + dt * 64 + jc;
        union { half8 v; uint4 u; } p0, p1;
        p0.v = cvt8h(src);
        p1.v = cvt8h(src + 8);
        *(uint4*)&tile[i][jc]     = p0.u;
        *(uint4*)&tile[i][jc + 8] = p1.u;
        unsigned short* dh = reinterpret_cast<unsigned short*>(FiH)
            + ((size_t)b * Mm + mt * 64 + i) * Dd + dt * 64 + jc;
        *(uint4*)dh       = p0.u;
        *(uint4*)(dh + 8) = p1.u;
    }
    __syncthreads();
    {
        const int d = t >> 2, mc = (t & 3) * 16;
        unsigned short* dst = reinterpret_cast<unsigned short*>(FiT)
            + ((size_t)b * Dd + dt * 64 + d) * Mm + mt * 64 + mc;
        union { uint4 v[2]; unsigned short s[16]; } u;
#pragma unroll
        for (int s = 0; s < 16; ++s) u.s[s] = tile[mc + s][d];
        *(uint4*)dst       = u.v[0];
        *(uint4*)(dst + 8) = u.v[1];
    }
}

// ---------------------------------------------------------------------------
// Kernel 2 (qproj): q = fp16( x @ W^T + b ), 3-term fp16-split MFMA.
// grid 256 x 128 thr; wave w computes 32 rows (2 row-tiles), all 256 cols.
// Wh/Wl precomputed by prep (no per-block VALU splitting of W).
// ---------------------------------------------------------------------------
__global__ __launch_bounds__(128, 2)
void qproj_kernel(const float* __restrict__ x, const _Float16* __restrict__ Wh,
                  const _Float16* __restrict__ Wl, const float* __restrict__ bias,
                  _Float16* __restrict__ q)
{
    const int lane = threadIdx.x & 63;
    const int w = threadIdx.x >> 6;
    const int lo = lane & 15, hi = lane >> 4;
    const long r0 = (long)blockIdx.x * 64 + w * 32;

    floatx4 acc[2][16];
#pragma unroll
    for (int rt = 0; rt < 2; ++rt)
#pragma unroll
        for (int j = 0; j < 16; ++j) acc[rt][j] = (floatx4)0.0f;

#pragma unroll
    for (int kk = 0; kk < 8; ++kk) {
        half8 ah[2], al[2];
#pragma unroll
        for (int rt = 0; rt < 2; ++rt)
            cvt8h_split(x + (size_t)(r0 + rt * 16 + lo) * Dd + kk * 32 + hi * 8, ah[rt], al[rt]);
#pragma unroll
        for (int j = 0; j < 16; ++j) {
            const size_t wb = (size_t)(j * 16 + lo) * Dd + kk * 32 + hi * 8;
            half8 bh = *reinterpret_cast<const half8*>(Wh + wb);
            half8 bl = *reinterpret_cast<const half8*>(Wl + wb);
#pragma unroll
            for (int rt = 0; rt < 2; ++rt) {
                acc[rt][j] = MFMA16H(ah[rt], bh, acc[rt][j]);
                acc[rt][j] = MFMA16H(ah[rt], bl, acc[rt][j]);
                acc[rt][j] = MFMA16H(al[rt], bh, acc[rt][j]);
            }
        }
    }
#pragma unroll
    for (int j = 0; j < 16; ++j) {
        float bv = bias[j * 16 + lo];
#pragma unroll
        for (int rt = 0; rt < 2; ++rt)
#pragma unroll
            for (int r = 0; r < 4; ++r)
                q[(size_t)(r0 + rt * 16 + hi * 4 + r) * Dd + j * 16 + lo] =
                    (_Float16)(acc[rt][j][r] + bv);
    }
}

// ---------------------------------------------------------------------------
// Kernel 3 (flash): m97-style K-loop. grid 256 (b=bid&7 XCD-affine), 128 thr.
// 2 waves x 32 q-rows = 64 rows/block; 64-key tiles, double-buffered LDS via
// global_load_lds; 16B-chunk XOR swizzle (c ^= row&7) for bank-uniform b128.
// ---------------------------------------------------------------------------
__global__ __launch_bounds__(128, 1)
void flash_kernel(const _Float16* __restrict__ q, const _Float16* __restrict__ FiH,
                  const _Float16* __restrict__ FiT, float* __restrict__ out)
{
    __shared__ __align__(16) _Float16 sFi[2][64 * 256];   // [key][d] swizzled, 32 KB ea
    __shared__ __align__(16) _Float16 sFiT[2][256 * 64];  // [d][key] swizzled, 32 KB ea
    __shared__ __align__(16) _Float16 sP[2][32][72];      // per-wave P [n][m], pad 64->72

    const int bid = blockIdx.x;
    const int b  = bid & 7;
    const int nt = bid >> 3;
    const int tid = threadIdx.x;
    const int lane = tid & 63, w = tid >> 6;
    const int lo = lane & 15, hi = lane >> 4;
    const long nbase = (long)nt * 64 + w * 32;

    const _Float16* fH = FiH + (size_t)b * Mm * Dd;
    const _Float16* fT = FiT + (size_t)b * Dd * Mm;

    // Q fragments (A layout: A[m=lo][k=hi*8+j]), 2 row-tiles x 8 k-chunks
    half8 qf[2][8];
    const _Float16* qb = q + ((size_t)b * Nn + nbase + lo) * Dd + hi * 8;
#pragma unroll
    for (int rt = 0; rt < 2; ++rt)
#pragma unroll
        for (int kk = 0; kk < 8; ++kk)
            qf[rt][kk] = *reinterpret_cast<const half8*>(qb + rt * 16 * Dd + kk * 32);

    floatx4 o[2][16];
#pragma unroll
    for (int rt = 0; rt < 2; ++rt)
#pragma unroll
        for (int t = 0; t < 16; ++t) o[rt][t] = (floatx4)0.0f;
    float m_i[2][4], l_i[2][4];
#pragma unroll
    for (int rt = 0; rt < 2; ++rt)
#pragma unroll
        for (int r = 0; r < 4; ++r) { m_i[rt][r] = -INFINITY; l_i[rt][r] = 0.f; }

    // DMA lane decomposition (wave-uniform LDS bases, per-lane gptr)
    const int fiR = lane >> 5, fiC = lane & 31;   // sFi: 2 rows x 32 chunks / instr
    const int ftR = lane >> 3, ftC = lane & 7;    // sFiT: 8 rows x 8 chunks / instr

    auto stage = [&](int it, int bb) {
        const int key0 = it * 64;
#pragma unroll
        for (int i = 0; i < 16; ++i) {
            const int rbase = w * 32 + i * 2;
            const int r = rbase + fiR;
            const _Float16* gp = fH + (size_t)(key0 + r) * Dd + ((fiC ^ (r & 7)) * 8);
            async16(gp, &sFi[bb][rbase * 256]);
        }
#pragma unroll
        for (int i = 0; i < 16; ++i) {
            const int rbase = w * 128 + i * 8;
            const int r = rbase + ftR;
            const _Float16* gp = fT + (size_t)r * Mm + key0 + ((ftC ^ (r & 7)) * 8);
            async16(gp, &sFiT[bb][rbase * 64]);
        }
    };

    stage(0, 0);

    for (int it = 0; it < 32; ++it) {
        const int bb = it & 1;
        __syncthreads();                 // vmcnt(0) drain: tile `it` now in LDS
        if (it + 1 < 32) stage(it + 1, bb ^ 1);   // prefetch overlaps compute

        // ---- S = q . Fi^T : 4 key-subtiles x 8 k-chunks, both row-tiles
        floatx4 s[2][4];
#pragma unroll
        for (int rt = 0; rt < 2; ++rt)
#pragma unroll
            for (int st = 0; st < 4; ++st) s[rt][st] = (floatx4)0.0f;
#pragma unroll
        for (int st = 0; st < 4; ++st) {
            const int row = st * 16 + lo;
#pragma unroll
            for (int kk = 0; kk < 8; ++kk) {
                half8 bv = *reinterpret_cast<const half8*>(
                    &sFi[bb][row * 256 + (((kk * 4 + hi) ^ (lo & 7)) * 8)]);
                s[0][st] = MFMA16H(qf[0][kk], bv, s[0][st]);
                s[1][st] = MFMA16H(qf[1][kk], bv, s[1][st]);
            }
        }

        // ---- online softmax (C layout: col=lo=key, row=hi*4+r)
        float alpha[2][4];
#pragma unroll
        for (int rt = 0; rt < 2; ++rt) {
#pragma unroll
            for (int r = 0; r < 4; ++r) {
                float mc = fmaxf(fmaxf(s[rt][0][r], s[rt][1][r]),
                                 fmaxf(s[rt][2][r], s[rt][3][r]));
                mc = fmaxf(mc, __shfl_xor(mc, 1));
                mc = fmaxf(mc, __shfl_xor(mc, 2));
                mc = fmaxf(mc, __shfl_xor(mc, 4));
                mc = fmaxf(mc, __shfl_xor(mc, 8));
                const float mnew = fmaxf(m_i[rt][r], mc);
                alpha[rt][r] = __expf(m_i[rt][r] - mnew);
                float ps = 0.f;
#pragma unroll
                for (int st = 0; st < 4; ++st) {
                    // round p to fp16 FIRST; l sums ROUNDED values so PV numerator
                    // and denominator use identical weights.
                    _Float16 pb = (_Float16)__expf(s[rt][st][r] - mnew);
                    ps += (float)pb;
                    sP[w][rt * 16 + hi * 4 + r][st * 16 + lo] = pb;
                }
                ps += __shfl_xor(ps, 1);
                ps += __shfl_xor(ps, 2);
                ps += __shfl_xor(ps, 4);
                ps += __shfl_xor(ps, 8);
                l_i[rt][r] = l_i[rt][r] * alpha[rt][r] + ps;
                m_i[rt][r] = mnew;
            }
        }
#pragma unroll
        for (int rt = 0; rt < 2; ++rt)
#pragma unroll
            for (int t = 0; t < 16; ++t) {
                floatx4 ot = o[rt][t];
#pragma unroll
                for (int r = 0; r < 4; ++r) ot[r] *= alpha[rt][r];
                o[rt][t] = ot;
            }

        // ---- O += P @ Fi : K=64 (2 chunks); B from swizzled sFiT
#pragma unroll
        for (int kc = 0; kc < 2; ++kc) {
            half8 pa0 = *reinterpret_cast<const half8*>(&sP[w][lo][kc * 32 + hi * 8]);
            half8 pa1 = *reinterpret_cast<const half8*>(&sP[w][16 + lo][kc * 32 + hi * 8]);
#pragma unroll
            for (int t = 0; t < 16; ++t) {
                const int drow = t * 16 + lo;
                half8 bv = *reinterpret_cast<const half8*>(
                    &sFiT[bb][drow * 64 + (((kc * 4 + hi) ^ (lo & 7)) * 8)]);
                o[0][t] = MFMA16H(pa0, bv, o[0][t]);
                o[1][t] = MFMA16H(pa1, bv, o[1][t]);
            }
        }
    }

    // ---- epilogue: O / l, store fp32
#pragma unroll
    for (int rt = 0; rt < 2; ++rt)
#pragma unroll
        for (int r = 0; r < 4; ++r) {
            const float inv = 1.0f / l_i[rt][r];
            float* orow = out + ((size_t)b * Nn + nbase + rt * 16 + hi * 4 + r) * Dd;
#pragma unroll
            for (int t = 0; t < 16; ++t)
                orow[t * 16 + lo] = o[rt][t][r] * inv;
        }
}

// ---------------------------------------------------------------------------
extern "C" void kernel_launch(void* const* d_in, const int* in_sizes, int n_in,
                              void* d_out, int out_size, void* d_ws, size_t ws_size,
                              hipStream_t stream)
{
    const float* x    = (const float*)d_in[0];
    const float* Fi   = (const float*)d_in[1];
    const float* W    = (const float*)d_in[2];
    const float* bias = (const float*)d_in[3];
    float* out = (float*)d_out;

    _Float16* q_ws = (_Float16*)d_ws;                               // 8.4 MB
    _Float16* FiH  = q_ws + (size_t)Bb * Nn * Dd;                   // 8.4 MB
    _Float16* FiT  = FiH + (size_t)Bb * Mm * Dd;                    // 8.4 MB
    _Float16* Wh   = FiT + (size_t)Bb * Mm * Dd;                    // 128 KB
    _Float16* Wl   = Wh + (size_t)Dd * Dd;                          // 128 KB

    hipLaunchKernelGGL(prep_kernel, dim3(1056), dim3(256), 0, stream, Fi, W, FiH, FiT, Wh, Wl);
    hipLaunchKernelGGL(qproj_kernel, dim3(256), dim3(128), 0, stream, x, Wh, Wl, bias, q_ws);
    hipLaunchKernelGGL(flash_kernel, dim3(256), dim3(128), 0, stream, q_ws, FiH, FiT, out);
}

// Round 6
// 246.976 us; speedup vs baseline: 1.2748x; 1.2748x over previous
//
#include <hip/hip_runtime.h>
#include <hip/hip_bf16.h>

typedef _Float16 half8 __attribute__((ext_vector_type(8)));
typedef float floatx4 __attribute__((ext_vector_type(4)));

#define MFMA16H(a, b, c) __builtin_amdgcn_mfma_f32_16x16x32_f16((a), (b), (c), 0, 0, 0)

static constexpr int Bb = 8, Nn = 2048, Mm = 2048, Dd = 256;
static constexpr int FT_ROWS = 272;   // 256 d-rows + ones-row(256) + zeros(257..271)

// async global->LDS DMA, 16B/lane. LDS dest = wave-uniform base + lane*16.
__device__ inline void async16(const void* g, void* l)
{
    __builtin_amdgcn_global_load_lds((const __attribute__((address_space(1))) unsigned int*)g,
                                     (__attribute__((address_space(3))) unsigned int*)l,
                                     16, 0, 0);
}

__device__ inline half8 cvt8h(const float* __restrict__ p)
{
    float4 f0 = *reinterpret_cast<const float4*>(p);
    float4 f1 = *reinterpret_cast<const float4*>(p + 4);
    half8 r;
    r[0] = (_Float16)f0.x; r[1] = (_Float16)f0.y; r[2] = (_Float16)f0.z; r[3] = (_Float16)f0.w;
    r[4] = (_Float16)f1.x; r[5] = (_Float16)f1.y; r[6] = (_Float16)f1.z; r[7] = (_Float16)f1.w;
    return r;
}

__device__ inline void cvt8h_split(const float* __restrict__ p, half8& h, half8& l)
{
    float4 f0 = *reinterpret_cast<const float4*>(p);
    float4 f1 = *reinterpret_cast<const float4*>(p + 4);
    float f[8] = {f0.x, f0.y, f0.z, f0.w, f1.x, f1.y, f1.z, f1.w};
#pragma unroll
    for (int i = 0; i < 8; ++i) {
        _Float16 hh = (_Float16)f[i];
        h[i] = hh;
        l[i] = (_Float16)(f[i] - (float)hh);
    }
}

// ---------------------------------------------------------------------------
// prep: [0,1024)   Fi -> FiH fp16 + FiT fp16 transpose (272-row pitch)
//       [1024,1056) W -> Wh/Wl fp16 hi/lo split
//       [1056,1120) FiT extra rows: row 256 = 1.0, rows 257..271 = 0
// ---------------------------------------------------------------------------
__global__ __launch_bounds__(256, 4)
void prep_kernel(const float* __restrict__ Fi, const float* __restrict__ W,
                 _Float16* __restrict__ FiH, _Float16* __restrict__ FiT,
                 _Float16* __restrict__ Wh, _Float16* __restrict__ Wl)
{
    const int bid = blockIdx.x;
    const int t = threadIdx.x;

    if (bid >= 1056) {                      // FiT extra rows
        const int idx = (bid - 1056) * 256 + t;
        const long e = (long)idx * 16;
        const int b  = (int)(e >> 15);
        const int rem = (int)(e & 32767);
        const int rr = rem >> 11;
        const int key = rem & 2047;
        _Float16 v = (rr == 0) ? (_Float16)1.0f : (_Float16)0.0f;
        union { half8 h; uint4 u; } pk;
#pragma unroll
        for (int i = 0; i < 8; ++i) pk.h[i] = v;
        unsigned short* dst = reinterpret_cast<unsigned short*>(FiT)
            + ((size_t)b * FT_ROWS + 256 + rr) * Mm + key;
        *(uint4*)dst       = pk.u;
        *(uint4*)(dst + 8) = pk.u;
        return;
    }
    if (bid >= 1024) {                      // W split
        const size_t base = (size_t)(bid - 1024) * 2048 + t * 8;
        half8 h, l;
        cvt8h_split(W + base, h, l);
        *(half8*)(Wh + base) = h;
        *(half8*)(Wl + base) = l;
        return;
    }

    __shared__ __align__(16) unsigned short tile[64][72];
    const int b  = bid >> 7;
    const int mt = (bid >> 2) & 31;
    const int dt = bid & 3;
    {
        const int i = t >> 2, jc = (t & 3) * 16;
        const float* src = Fi + ((size_t)b * Mm + mt * 64 + i) * Dd + dt * 64 + jc;
        union { half8 v; uint4 u; } p0, p1;
        p0.v = cvt8h(src);
        p1.v = cvt8h(src + 8);
        *(uint4*)&tile[i][jc]     = p0.u;
        *(uint4*)&tile[i][jc + 8] = p1.u;
        unsigned short* dh = reinterpret_cast<unsigned short*>(FiH)
            + ((size_t)b * Mm + mt * 64 + i) * Dd + dt * 64 + jc;
        *(uint4*)dh       = p0.u;
        *(uint4*)(dh + 8) = p1.u;
    }
    __syncthreads();
    {
        const int d = t >> 2, mc = (t & 3) * 16;
        unsigned short* dst = reinterpret_cast<unsigned short*>(FiT)
            + ((size_t)b * FT_ROWS + dt * 64 + d) * Mm + mt * 64 + mc;
        union { uint4 v[2]; unsigned short s[16]; } u;
#pragma unroll
        for (int s = 0; s < 16; ++s) u.s[s] = tile[mc + s][d];
        *(uint4*)dst       = u.v[0];
        *(uint4*)(dst + 8) = u.v[1];
    }
}

// ---------------------------------------------------------------------------
// qproj: q = fp16( x @ W^T + b ), 3-term fp16-split MFMA.
// grid 512 x 128 thr: block = 32 rows; wave w = column half (8 j-tiles).
// ---------------------------------------------------------------------------
__global__ __launch_bounds__(128, 2)
void qproj_kernel(const float* __restrict__ x, const _Float16* __restrict__ Wh,
                  const _Float16* __restrict__ Wl, const float* __restrict__ bias,
                  _Float16* __restrict__ q)
{
    const int lane = threadIdx.x & 63;
    const int w = threadIdx.x >> 6;
    const int lo = lane & 15, hi = lane >> 4;
    const long r0 = (long)blockIdx.x * 32;

    floatx4 acc[2][8];
#pragma unroll
    for (int rt = 0; rt < 2; ++rt)
#pragma unroll
        for (int j = 0; j < 8; ++j) acc[rt][j] = (floatx4)0.0f;

#pragma unroll
    for (int kk = 0; kk < 8; ++kk) {
        half8 ah[2], al[2];
#pragma unroll
        for (int rt = 0; rt < 2; ++rt)
            cvt8h_split(x + (size_t)(r0 + rt * 16 + lo) * Dd + kk * 32 + hi * 8, ah[rt], al[rt]);
#pragma unroll
        for (int j = 0; j < 8; ++j) {
            const int e = (w * 8 + j) * 16 + lo;
            const size_t wb = (size_t)e * Dd + kk * 32 + hi * 8;
            half8 bh = *reinterpret_cast<const half8*>(Wh + wb);
            half8 bl = *reinterpret_cast<const half8*>(Wl + wb);
#pragma unroll
            for (int rt = 0; rt < 2; ++rt) {
                acc[rt][j] = MFMA16H(ah[rt], bh, acc[rt][j]);
                acc[rt][j] = MFMA16H(ah[rt], bl, acc[rt][j]);
                acc[rt][j] = MFMA16H(al[rt], bh, acc[rt][j]);
            }
        }
    }
#pragma unroll
    for (int j = 0; j < 8; ++j) {
        const int e = (w * 8 + j) * 16 + lo;
        const float bv = bias[e];
#pragma unroll
        for (int rt = 0; rt < 2; ++rt)
#pragma unroll
            for (int r = 0; r < 4; ++r)
                q[(size_t)(r0 + rt * 16 + hi * 4 + r) * Dd + e] = (_Float16)(acc[rt][j][r] + bv);
    }
}

// ---------------------------------------------------------------------------
// flash: grid 512 = 8b x 16nt x 4kh, 256 thr (4 waves x 32 rows = 128 rows).
// Each block: 512 keys (16 iters x 32), single-buffer LDS via global_load_lds,
// m97 2-barrier loop. l computed by PV MFMA via ones-column (FiT row 256).
// Emits fp16 o-partials + fp32 m/l partials, merged by merge_kernel.
// ---------------------------------------------------------------------------
__global__ __launch_bounds__(256, 2)
void flash_kernel(const _Float16* __restrict__ q, const _Float16* __restrict__ FiH,
                  const _Float16* __restrict__ FiT, _Float16* __restrict__ o_part,
                  float* __restrict__ m_part, float* __restrict__ l_part)
{
    __shared__ __align__(16) _Float16 sFi[32 * 256];       // [key][d], 16B-chunk XOR swizzle (r&7)
    __shared__ __align__(16) _Float16 sFiT[FT_ROWS * 32];  // [d][key], XOR swizzle (r&3)
    __shared__ __align__(16) _Float16 sP[4][32 * 40];      // per-wave P [qrow][key], pad 32->40

    const int bid = blockIdx.x;
    const int b  = bid & 7;
    const int u  = bid >> 3;
    const int nt = u & 15;
    const int kh = u >> 4;
    const int tid = threadIdx.x;
    const int lane = tid & 63, w = tid >> 6;
    const int lo = lane & 15, hi = lane >> 4;
    const int nbase = nt * 128 + w * 32;

    const _Float16* fH = FiH + (size_t)b * Mm * Dd;
    const _Float16* fT = FiT + (size_t)b * FT_ROWS * Mm;

    // Q fragments (A layout: A[m=lo][k=hi*8+j])
    half8 qf[2][8];
    const _Float16* qb = q + ((size_t)b * Nn + nbase + lo) * Dd + hi * 8;
#pragma unroll
    for (int rt = 0; rt < 2; ++rt)
#pragma unroll
        for (int kk = 0; kk < 8; ++kk)
            qf[rt][kk] = *reinterpret_cast<const half8*>(qb + rt * 16 * Dd + kk * 32);

    floatx4 o[2][16];
    floatx4 ol[2];   // l-accumulator tile (ones-column)
#pragma unroll
    for (int rt = 0; rt < 2; ++rt) {
#pragma unroll
        for (int t = 0; t < 16; ++t) o[rt][t] = (floatx4)0.0f;
        ol[rt] = (floatx4)0.0f;
    }
    float m_i[2][4];
#pragma unroll
    for (int rt = 0; rt < 2; ++rt)
#pragma unroll
        for (int r = 0; r < 4; ++r) m_i[rt][r] = -INFINITY;

    for (int it = 0; it < 16; ++it) {
        const int key0 = kh * 512 + it * 32;

        __syncthreads();   // all waves done reading previous tile
        // ---- stage (sFi: 16 instrs, sFiT: 17 instrs, split across 4 waves)
#pragma unroll
        for (int j = 0; j < 4; ++j) {
            const int rbase = (w * 4 + j) * 2;
            const int r = rbase + (lane >> 5);
            const int gc = (lane & 31) ^ (r & 7);
            async16(fH + (size_t)(key0 + r) * Dd + gc * 8, &sFi[rbase * 256]);
        }
#pragma unroll
        for (int j = 0; j < 4; ++j) {
            const int rbase = (w + j * 4) * 16;
            const int r = rbase + (lane >> 2);
            const int gc = (lane & 3) ^ (r & 3);
            async16(fT + (size_t)r * Mm + key0 + gc * 8, &sFiT[rbase * 32]);
        }
        if (w == 0) {
            const int r = 256 + (lane >> 2);
            const int gc = (lane & 3) ^ (r & 3);
            async16(fT + (size_t)r * Mm + key0 + gc * 8, &sFiT[256 * 32]);
        }
        __syncthreads();   // DMA drained: tile `it` in LDS

        // ---- S = q . Fi^T : 2 key-subtiles x 8 k-chunks, both row-tiles
        floatx4 s[2][2];
#pragma unroll
        for (int rt = 0; rt < 2; ++rt)
#pragma unroll
            for (int st = 0; st < 2; ++st) s[rt][st] = (floatx4)0.0f;
#pragma unroll
        for (int st = 0; st < 2; ++st) {
            const int row = st * 16 + lo;
#pragma unroll
            for (int kk = 0; kk < 8; ++kk) {
                half8 bv = *reinterpret_cast<const half8*>(
                    &sFi[row * 256 + (((kk * 4 + hi) ^ (lo & 7)) * 8)]);
                s[0][st] = MFMA16H(qf[0][kk], bv, s[0][st]);
                s[1][st] = MFMA16H(qf[1][kk], bv, s[1][st]);
            }
        }

        // ---- online max (C layout: col=lo=key, row=hi*4+r); conditional rescale
        float mn[2][4];
        bool chg = false;
#pragma unroll
        for (int rt = 0; rt < 2; ++rt)
#pragma unroll
            for (int r = 0; r < 4; ++r) {
                float mc = fmaxf(s[rt][0][r], s[rt][1][r]);
                mc = fmaxf(mc, __shfl_xor(mc, 1));
                mc = fmaxf(mc, __shfl_xor(mc, 2));
                mc = fmaxf(mc, __shfl_xor(mc, 4));
                mc = fmaxf(mc, __shfl_xor(mc, 8));
                mn[rt][r] = fmaxf(m_i[rt][r], mc);
                chg = chg || (mn[rt][r] > m_i[rt][r]);
            }
        if (__any(chg)) {
#pragma unroll
            for (int rt = 0; rt < 2; ++rt) {
                float al4[4];
#pragma unroll
                for (int r = 0; r < 4; ++r) {
                    al4[r] = __expf(m_i[rt][r] - mn[rt][r]);
                    m_i[rt][r] = mn[rt][r];
                }
#pragma unroll
                for (int t = 0; t < 16; ++t) {
                    floatx4 ot = o[rt][t];
#pragma unroll
                    for (int r = 0; r < 4; ++r) ot[r] *= al4[r];
                    o[rt][t] = ot;
                }
#pragma unroll
                for (int r = 0; r < 4; ++r) ol[rt][r] *= al4[r];
            }
        }
        // ---- p (fp16) -> sP; l comes from the ones-column MFMA below
#pragma unroll
        for (int rt = 0; rt < 2; ++rt)
#pragma unroll
            for (int r = 0; r < 4; ++r) {
                _Float16 p0 = (_Float16)__expf(s[rt][0][r] - m_i[rt][r]);
                _Float16 p1 = (_Float16)__expf(s[rt][1][r] - m_i[rt][r]);
                sP[w][(rt * 16 + hi * 4 + r) * 40 + lo]      = p0;
                sP[w][(rt * 16 + hi * 4 + r) * 40 + 16 + lo] = p1;
            }

        // ---- O += P @ Fi (K=32); B from swizzled sFiT; t=16 = ones-column -> l
        half8 pa0 = *reinterpret_cast<const half8*>(&sP[w][lo * 40 + hi * 8]);
        half8 pa1 = *reinterpret_cast<const half8*>(&sP[w][(16 + lo) * 40 + hi * 8]);
#pragma unroll
        for (int t = 0; t < 16; ++t) {
            half8 bv = *reinterpret_cast<const half8*>(
                &sFiT[(t * 16 + lo) * 32 + ((hi ^ (lo & 3)) * 8)]);
            o[0][t] = MFMA16H(pa0, bv, o[0][t]);
            o[1][t] = MFMA16H(pa1, bv, o[1][t]);
        }
        {
            half8 bvl = *reinterpret_cast<const half8*>(
                &sFiT[(256 + lo) * 32 + ((hi ^ (lo & 3)) * 8)]);
            ol[0] = MFMA16H(pa0, bvl, ol[0]);
            ol[1] = MFMA16H(pa1, bvl, ol[1]);
        }
    }

    // ---- epilogue: store fp16 o-partial + fp32 m/l partials (raw, merge normalizes)
#pragma unroll
    for (int rt = 0; rt < 2; ++rt)
#pragma unroll
        for (int r = 0; r < 4; ++r) {
            const long gq = (long)b * Nn + nbase + rt * 16 + hi * 4 + r;
            const size_t obase = ((size_t)kh * (Bb * Nn) + gq) * Dd;
#pragma unroll
            for (int t = 0; t < 16; ++t)
                o_part[obase + t * 16 + lo] = (_Float16)o[rt][t][r];
            if (lo == 0) {
                m_part[(size_t)kh * (Bb * Nn) + gq] = m_i[rt][r];
                l_part[(size_t)kh * (Bb * Nn) + gq] = ol[rt][r];
            }
        }
}

// ---------------------------------------------------------------------------
// merge: combine 4 KV-split partials. grid 16384 x 256 thr (1 row / block).
// ---------------------------------------------------------------------------
__global__ __launch_bounds__(256, 8)
void merge_kernel(const _Float16* __restrict__ o_part, const float* __restrict__ m_part,
                  const float* __restrict__ l_part, float* __restrict__ out)
{
    const int row = blockIdx.x;
    const int col = threadIdx.x;
    float m[4], l[4];
#pragma unroll
    for (int k = 0; k < 4; ++k) {
        m[k] = m_part[(size_t)k * (Bb * Nn) + row];
        l[k] = l_part[(size_t)k * (Bb * Nn) + row];
    }
    float M = fmaxf(fmaxf(m[0], m[1]), fmaxf(m[2], m[3]));
    float denom = 0.f, acc = 0.f;
#pragma unroll
    for (int k = 0; k < 4; ++k) {
        const float wk = __expf(m[k] - M);
        denom += wk * l[k];
        acc += wk * (float)o_part[((size_t)k * (Bb * Nn) + row) * Dd + col];
    }
    out[(size_t)row * Dd + col] = acc / denom;
}

// ---------------------------------------------------------------------------
extern "C" void kernel_launch(void* const* d_in, const int* in_sizes, int n_in,
                              void* d_out, int out_size, void* d_ws, size_t ws_size,
                              hipStream_t stream)
{
    const float* x    = (const float*)d_in[0];
    const float* Fi   = (const float*)d_in[1];
    const float* W    = (const float*)d_in[2];
    const float* bias = (const float*)d_in[3];
    float* out = (float*)d_out;

    _Float16* q_ws = (_Float16*)d_ws;                                // 8.4 MB
    _Float16* FiH  = q_ws + (size_t)Bb * Nn * Dd;                    // 8.4 MB
    _Float16* FiT  = FiH + (size_t)Bb * Mm * Dd;                     // 8.9 MB (272 rows)
    _Float16* Wh   = FiT + (size_t)Bb * FT_ROWS * Mm;                // 128 KB
    _Float16* Wl   = Wh + (size_t)Dd * Dd;                           // 128 KB
    _Float16* o_part = Wl + (size_t)Dd * Dd;                         // 33.6 MB
    float* m_part  = (float*)(o_part + (size_t)4 * Bb * Nn * Dd);    // 256 KB
    float* l_part  = m_part + (size_t)4 * Bb * Nn;                   // 256 KB

    hipLaunchKernelGGL(prep_kernel, dim3(1120), dim3(256), 0, stream, Fi, W, FiH, FiT, Wh, Wl);
    hipLaunchKernelGGL(qproj_kernel, dim3(512), dim3(128), 0, stream, x, Wh, Wl, bias, q_ws);
    hipLaunchKernelGGL(flash_kernel, dim3(512), dim3(256), 0, stream, q_ws, FiH, FiT,
                       o_part, m_part, l_part);
    hipLaunchKernelGGL(merge_kernel, dim3(16384), dim3(256), 0, stream, o_part, m_part, l_part, out);
}

// Round 7
// 231.929 us; speedup vs baseline: 1.3575x; 1.0649x over previous
//
#include <hip/hip_runtime.h>
#include <hip/hip_bf16.h>

typedef _Float16 half8 __attribute__((ext_vector_type(8)));
typedef float floatx4 __attribute__((ext_vector_type(4)));

#define MFMA16H(a, b, c) __builtin_amdgcn_mfma_f32_16x16x32_f16((a), (b), (c), 0, 0, 0)

static constexpr int Bb = 8, Nn = 2048, Mm = 2048, Dd = 256;

// async global->LDS DMA, 16B/lane. LDS dest = wave-uniform base + lane*16.
__device__ inline void async16(const void* g, void* l)
{
    __builtin_amdgcn_global_load_lds((const __attribute__((address_space(1))) unsigned int*)g,
                                     (__attribute__((address_space(3))) unsigned int*)l,
                                     16, 0, 0);
}

__device__ inline half8 cvt8h(const float* __restrict__ p)
{
    float4 f0 = *reinterpret_cast<const float4*>(p);
    float4 f1 = *reinterpret_cast<const float4*>(p + 4);
    half8 r;
    r[0] = (_Float16)f0.x; r[1] = (_Float16)f0.y; r[2] = (_Float16)f0.z; r[3] = (_Float16)f0.w;
    r[4] = (_Float16)f1.x; r[5] = (_Float16)f1.y; r[6] = (_Float16)f1.z; r[7] = (_Float16)f1.w;
    return r;
}

__device__ inline void cvt8h_split(const float* __restrict__ p, half8& h, half8& l)
{
    float4 f0 = *reinterpret_cast<const float4*>(p);
    float4 f1 = *reinterpret_cast<const float4*>(p + 4);
    float f[8] = {f0.x, f0.y, f0.z, f0.w, f1.x, f1.y, f1.z, f1.w};
#pragma unroll
    for (int i = 0; i < 8; ++i) {
        _Float16 hh = (_Float16)f[i];
        h[i] = hh;
        l[i] = (_Float16)(f[i] - (float)hh);
    }
}

// ---------------------------------------------------------------------------
// prep: [0,1024)   Fi -> FiH fp16 + FiT fp16 transpose
//       [1024,1056) W -> Wh/Wl fp16 hi/lo split
// ---------------------------------------------------------------------------
__global__ __launch_bounds__(256, 4)
void prep_kernel(const float* __restrict__ Fi, const float* __restrict__ W,
                 _Float16* __restrict__ FiH, _Float16* __restrict__ FiT,
                 _Float16* __restrict__ Wh, _Float16* __restrict__ Wl)
{
    const int bid = blockIdx.x;
    const int t = threadIdx.x;

    if (bid >= 1024) {                      // W split
        const size_t base = (size_t)(bid - 1024) * 2048 + t * 8;
        half8 h, l;
        cvt8h_split(W + base, h, l);
        *(half8*)(Wh + base) = h;
        *(half8*)(Wl + base) = l;
        return;
    }

    __shared__ __align__(16) unsigned short tile[64][72];
    const int b  = bid >> 7;
    const int mt = (bid >> 2) & 31;
    const int dt = bid & 3;
    {
        const int i = t >> 2, jc = (t & 3) * 16;
        const float* src = Fi + ((size_t)b * Mm + mt * 64 + i) * Dd + dt * 64 + jc;
        union { half8 v; uint4 u; } p0, p1;
        p0.v = cvt8h(src);
        p1.v = cvt8h(src + 8);
        *(uint4*)&tile[i][jc]     = p0.u;
        *(uint4*)&tile[i][jc + 8] = p1.u;
        unsigned short* dh = reinterpret_cast<unsigned short*>(FiH)
            + ((size_t)b * Mm + mt * 64 + i) * Dd + dt * 64 + jc;
        *(uint4*)dh       = p0.u;
        *(uint4*)(dh + 8) = p1.u;
    }
    __syncthreads();
    {
        const int d = t >> 2, mc = (t & 3) * 16;
        unsigned short* dst = reinterpret_cast<unsigned short*>(FiT)
            + ((size_t)b * Dd + dt * 64 + d) * Mm + mt * 64 + mc;
        union { uint4 v[2]; unsigned short s[16]; } u;
#pragma unroll
        for (int s = 0; s < 16; ++s) u.s[s] = tile[mc + s][d];
        *(uint4*)dst       = u.v[0];
        *(uint4*)(dst + 8) = u.v[1];
    }
}

// ---------------------------------------------------------------------------
// qproj: q = fp16( x @ W^T + b ), 3-term fp16-split MFMA.
// grid 1024 x 128 thr: block = 16 rows; wave w = column half (8 j-tiles).
// 4 blocks/CU co-resident (8 waves/CU).
// ---------------------------------------------------------------------------
__global__ __launch_bounds__(128, 4)
void qproj_kernel(const float* __restrict__ x, const _Float16* __restrict__ Wh,
                  const _Float16* __restrict__ Wl, const float* __restrict__ bias,
                  _Float16* __restrict__ q)
{
    const int lane = threadIdx.x & 63;
    const int w = threadIdx.x >> 6;
    const int lo = lane & 15, hi = lane >> 4;
    const long r0 = (long)blockIdx.x * 16;

    floatx4 acc[8];
#pragma unroll
    for (int j = 0; j < 8; ++j) acc[j] = (floatx4)0.0f;

#pragma unroll
    for (int kk = 0; kk < 8; ++kk) {
        half8 ah, al;
        cvt8h_split(x + (size_t)(r0 + lo) * Dd + kk * 32 + hi * 8, ah, al);
#pragma unroll
        for (int j = 0; j < 8; ++j) {
            const int e = (w * 8 + j) * 16 + lo;
            const size_t wb = (size_t)e * Dd + kk * 32 + hi * 8;
            half8 bh = *reinterpret_cast<const half8*>(Wh + wb);
            half8 bl = *reinterpret_cast<const half8*>(Wl + wb);
            acc[j] = MFMA16H(ah, bh, acc[j]);
            acc[j] = MFMA16H(ah, bl, acc[j]);
            acc[j] = MFMA16H(al, bh, acc[j]);
        }
    }
#pragma unroll
    for (int j = 0; j < 8; ++j) {
        const int e = (w * 8 + j) * 16 + lo;
        const float bv = bias[e];
#pragma unroll
        for (int r = 0; r < 4; ++r)
            q[(size_t)(r0 + hi * 4 + r) * Dd + e] = (_Float16)(acc[j][r] + bv);
    }
}

// ---------------------------------------------------------------------------
// flash: grid 512 = 8b x 16nt x 4kh, 256 thr (4 waves x 32 rows = 128 rows).
// 512 keys/block (16 iters x 32), TRUE double-buffer: statically distinct LDS
// arrays A/B + 2-unrolled loop so the compiler can prove the prefetch DMA
// doesn't alias the ds_reads (vmcnt(0) only at barriers, one phase of slack).
// l computed by PV MFMA against a constant all-ones B fragment.
// ---------------------------------------------------------------------------
__global__ __launch_bounds__(256, 2)
void flash_kernel(const _Float16* __restrict__ q, const _Float16* __restrict__ FiH,
                  const _Float16* __restrict__ FiT, _Float16* __restrict__ o_part,
                  float* __restrict__ m_part, float* __restrict__ l_part)
{
    __shared__ __align__(16) _Float16 sFiA[32 * 256];    // [key][d], chunk-XOR (r&7)
    __shared__ __align__(16) _Float16 sFiB[32 * 256];
    __shared__ __align__(16) _Float16 sFiTA[256 * 32];   // [d][key], chunk-XOR (r&3)
    __shared__ __align__(16) _Float16 sFiTB[256 * 32];
    __shared__ __align__(16) _Float16 sP[4][32 * 36];    // per-wave P, pitch 36

    const int bid = blockIdx.x;
    const int b  = bid & 7;
    const int u  = bid >> 3;
    const int nt = u & 15;
    const int kh = u >> 4;
    const int tid = threadIdx.x;
    const int lane = tid & 63, w = tid >> 6;
    const int lo = lane & 15, hi = lane >> 4;
    const int nbase = nt * 128 + w * 32;

    const _Float16* fH = FiH + (size_t)b * Mm * Dd;
    const _Float16* fT = FiT + (size_t)b * Dd * Mm;

    // Q fragments (A layout: A[m=lo][k=hi*8+j])
    half8 qf[2][8];
    const _Float16* qb = q + ((size_t)b * Nn + nbase + lo) * Dd + hi * 8;
#pragma unroll
    for (int rt = 0; rt < 2; ++rt)
#pragma unroll
        for (int kk = 0; kk < 8; ++kk)
            qf[rt][kk] = *reinterpret_cast<const half8*>(qb + rt * 16 * Dd + kk * 32);

    half8 ones;
#pragma unroll
    for (int i = 0; i < 8; ++i) ones[i] = (_Float16)1.0f;

    floatx4 o[2][16];
    floatx4 ol[2];
#pragma unroll
    for (int rt = 0; rt < 2; ++rt) {
#pragma unroll
        for (int t = 0; t < 16; ++t) o[rt][t] = (floatx4)0.0f;
        ol[rt] = (floatx4)0.0f;
    }
    float m_i[2][4];
#pragma unroll
    for (int rt = 0; rt < 2; ++rt)
#pragma unroll
        for (int r = 0; r < 4; ++r) m_i[rt][r] = -INFINITY;

    // DMA issue only — no LDS reads here, so aliasing is irrelevant.
    auto stage = [&](int it, _Float16* dFi, _Float16* dFiT) {
        const int key0 = kh * 512 + it * 32;
#pragma unroll
        for (int j = 0; j < 4; ++j) {
            const int rbase = (w * 4 + j) * 2;
            const int r = rbase + (lane >> 5);
            const int gc = (lane & 31) ^ (r & 7);
            async16(fH + (size_t)(key0 + r) * Dd + gc * 8, dFi + rbase * 256);
        }
#pragma unroll
        for (int j = 0; j < 4; ++j) {
            const int rbase = (w + j * 4) * 16;
            const int r = rbase + (lane >> 2);
            const int gc = (lane & 3) ^ (r & 3);
            async16(fT + (size_t)r * Mm + key0 + gc * 8, dFiT + rbase * 32);
        }
    };

    auto compute = [&](const _Float16* SFI, const _Float16* SFIT) {
        // ---- S = q . Fi^T : 2 key-subtiles x 8 k-chunks, both row-tiles
        floatx4 s[2][2];
#pragma unroll
        for (int rt = 0; rt < 2; ++rt)
#pragma unroll
            for (int st = 0; st < 2; ++st) s[rt][st] = (floatx4)0.0f;
#pragma unroll
        for (int st = 0; st < 2; ++st) {
            const int row = st * 16 + lo;
#pragma unroll
            for (int kk = 0; kk < 8; ++kk) {
                half8 bv = *reinterpret_cast<const half8*>(
                    SFI + row * 256 + (((kk * 4 + hi) ^ (lo & 7)) * 8));
                s[0][st] = MFMA16H(qf[0][kk], bv, s[0][st]);
                s[1][st] = MFMA16H(qf[1][kk], bv, s[1][st]);
            }
        }

        // ---- online max (C layout: col=lo=key, row=hi*4+r); conditional rescale
        float mn[2][4];
        bool chg = false;
#pragma unroll
        for (int rt = 0; rt < 2; ++rt)
#pragma unroll
            for (int r = 0; r < 4; ++r) {
                float mc = fmaxf(s[rt][0][r], s[rt][1][r]);
                mc = fmaxf(mc, __shfl_xor(mc, 1));
                mc = fmaxf(mc, __shfl_xor(mc, 2));
                mc = fmaxf(mc, __shfl_xor(mc, 4));
                mc = fmaxf(mc, __shfl_xor(mc, 8));
                mn[rt][r] = fmaxf(m_i[rt][r], mc);
                chg = chg || (mn[rt][r] > m_i[rt][r]);
            }
        if (__any(chg)) {
#pragma unroll
            for (int rt = 0; rt < 2; ++rt) {
                float al4[4];
#pragma unroll
                for (int r = 0; r < 4; ++r) {
                    al4[r] = __expf(m_i[rt][r] - mn[rt][r]);
                    m_i[rt][r] = mn[rt][r];
                }
#pragma unroll
                for (int t = 0; t < 16; ++t) {
                    floatx4 ot = o[rt][t];
#pragma unroll
                    for (int r = 0; r < 4; ++r) ot[r] *= al4[r];
                    o[rt][t] = ot;
                }
#pragma unroll
                for (int r = 0; r < 4; ++r) ol[rt][r] *= al4[r];
            }
        }
        // ---- p (fp16, round-first) -> sP (wave-private, no barrier)
#pragma unroll
        for (int rt = 0; rt < 2; ++rt)
#pragma unroll
            for (int r = 0; r < 4; ++r) {
                _Float16 p0 = (_Float16)__expf(s[rt][0][r] - m_i[rt][r]);
                _Float16 p1 = (_Float16)__expf(s[rt][1][r] - m_i[rt][r]);
                sP[w][(rt * 16 + hi * 4 + r) * 36 + lo]      = p0;
                sP[w][(rt * 16 + hi * 4 + r) * 36 + 16 + lo] = p1;
            }

        // ---- O += P @ Fi (K=32, one MFMA per d-tile); l via all-ones B-frag
        half8 pa0 = *reinterpret_cast<const half8*>(&sP[w][lo * 36 + hi * 8]);
        half8 pa1 = *reinterpret_cast<const half8*>(&sP[w][(16 + lo) * 36 + hi * 8]);
#pragma unroll
        for (int t = 0; t < 16; ++t) {
            half8 bv = *reinterpret_cast<const half8*>(
                SFIT + (t * 16 + lo) * 32 + ((hi ^ (lo & 3)) * 8));
            o[0][t] = MFMA16H(pa0, bv, o[0][t]);
            o[1][t] = MFMA16H(pa1, bv, o[1][t]);
        }
        ol[0] = MFMA16H(pa0, ones, ol[0]);
        ol[1] = MFMA16H(pa1, ones, ol[1]);
    };

    stage(0, sFiA, sFiTA);
    for (int it = 0; it < 16; it += 2) {
        __syncthreads();                        // drain A(it); all waves done with B
        stage(it + 1, sFiB, sFiTB);             // prefetch B — in flight during compute A
        compute(sFiA, sFiTA);
        __syncthreads();                        // drain B(it+1); all waves done with A
        if (it + 2 < 16) stage(it + 2, sFiA, sFiTA);
        compute(sFiB, sFiTB);
    }

    // ---- epilogue: fp16 o-partials + fp32 m/l partials (merge normalizes)
#pragma unroll
    for (int rt = 0; rt < 2; ++rt)
#pragma unroll
        for (int r = 0; r < 4; ++r) {
            const long gq = (long)b * Nn + nbase + rt * 16 + hi * 4 + r;
            const size_t obase = ((size_t)kh * (Bb * Nn) + gq) * Dd;
#pragma unroll
            for (int t = 0; t < 16; ++t)
                o_part[obase + t * 16 + lo] = (_Float16)o[rt][t][r];
            if (lo == 0) {
                m_part[(size_t)kh * (Bb * Nn) + gq] = m_i[rt][r];
                l_part[(size_t)kh * (Bb * Nn) + gq] = ol[rt][r];
            }
        }
}

// ---------------------------------------------------------------------------
// merge: combine 4 KV-split partials. grid 16384 x 256 thr (1 row / block).
// ---------------------------------------------------------------------------
__global__ __launch_bounds__(256, 8)
void merge_kernel(const _Float16* __restrict__ o_part, const float* __restrict__ m_part,
                  const float* __restrict__ l_part, float* __restrict__ out)
{
    const int row = blockIdx.x;
    const int col = threadIdx.x;
    float m[4], l[4];
#pragma unroll
    for (int k = 0; k < 4; ++k) {
        m[k] = m_part[(size_t)k * (Bb * Nn) + row];
        l[k] = l_part[(size_t)k * (Bb * Nn) + row];
    }
    float M = fmaxf(fmaxf(m[0], m[1]), fmaxf(m[2], m[3]));
    float denom = 0.f, acc = 0.f;
#pragma unroll
    for (int k = 0; k < 4; ++k) {
        const float wk = __expf(m[k] - M);
        denom += wk * l[k];
        acc += wk * (float)o_part[((size_t)k * (Bb * Nn) + row) * Dd + col];
    }
    out[(size_t)row * Dd + col] = acc / denom;
}

// ---------------------------------------------------------------------------
extern "C" void kernel_launch(void* const* d_in, const int* in_sizes, int n_in,
                              void* d_out, int out_size, void* d_ws, size_t ws_size,
                              hipStream_t stream)
{
    const float* x    = (const float*)d_in[0];
    const float* Fi   = (const float*)d_in[1];
    const float* W    = (const float*)d_in[2];
    const float* bias = (const float*)d_in[3];
    float* out = (float*)d_out;

    _Float16* q_ws = (_Float16*)d_ws;                                // 8.4 MB
    _Float16* FiH  = q_ws + (size_t)Bb * Nn * Dd;                    // 8.4 MB
    _Float16* FiT  = FiH + (size_t)Bb * Mm * Dd;                     // 8.4 MB
    _Float16* Wh   = FiT + (size_t)Bb * Dd * Mm;                     // 128 KB
    _Float16* Wl   = Wh + (size_t)Dd * Dd;                           // 128 KB
    _Float16* o_part = Wl + (size_t)Dd * Dd;                         // 33.6 MB
    float* m_part  = (float*)(o_part + (size_t)4 * Bb * Nn * Dd);    // 256 KB
    float* l_part  = m_part + (size_t)4 * Bb * Nn;                   // 256 KB

    hipLaunchKernelGGL(prep_kernel, dim3(1056), dim3(256), 0, stream, Fi, W, FiH, FiT, Wh, Wl);
    hipLaunchKernelGGL(qproj_kernel, dim3(1024), dim3(128), 0, stream, x, Wh, Wl, bias, q_ws);
    hipLaunchKernelGGL(flash_kernel, dim3(512), dim3(256), 0, stream, q_ws, FiH, FiT,
                       o_part, m_part, l_part);
    hipLaunchKernelGGL(merge_kernel, dim3(16384), dim3(256), 0, stream, o_part, m_part, l_part, out);
}

// Round 8
// 216.734 us; speedup vs baseline: 1.4527x; 1.0701x over previous
//
#include <hip/hip_runtime.h>
#include <hip/hip_bf16.h>

typedef _Float16 half8 __attribute__((ext_vector_type(8)));
typedef float floatx4 __attribute__((ext_vector_type(4)));

#define MFMA16H(a, b, c) __builtin_amdgcn_mfma_f32_16x16x32_f16((a), (b), (c), 0, 0, 0)

static constexpr int Bb = 8, Nn = 2048, Mm = 2048, Dd = 256;

// async global->LDS DMA, 16B/lane. LDS dest = wave-uniform base + lane*16.
__device__ inline void async16(const void* g, void* l)
{
    __builtin_amdgcn_global_load_lds((const __attribute__((address_space(1))) unsigned int*)g,
                                     (__attribute__((address_space(3))) unsigned int*)l,
                                     16, 0, 0);
}

__device__ inline half8 cvt8h(const float* __restrict__ p)
{
    float4 f0 = *reinterpret_cast<const float4*>(p);
    float4 f1 = *reinterpret_cast<const float4*>(p + 4);
    half8 r;
    r[0] = (_Float16)f0.x; r[1] = (_Float16)f0.y; r[2] = (_Float16)f0.z; r[3] = (_Float16)f0.w;
    r[4] = (_Float16)f1.x; r[5] = (_Float16)f1.y; r[6] = (_Float16)f1.z; r[7] = (_Float16)f1.w;
    return r;
}

__device__ inline void cvt8h_split(const float* __restrict__ p, half8& h, half8& l)
{
    float4 f0 = *reinterpret_cast<const float4*>(p);
    float4 f1 = *reinterpret_cast<const float4*>(p + 4);
    float f[8] = {f0.x, f0.y, f0.z, f0.w, f1.x, f1.y, f1.z, f1.w};
#pragma unroll
    for (int i = 0; i < 8; ++i) {
        _Float16 hh = (_Float16)f[i];
        h[i] = hh;
        l[i] = (_Float16)(f[i] - (float)hh);
    }
}

// ---------------------------------------------------------------------------
// prep: [0,1024)   Fi -> FiH fp16 + FiT fp16 transpose
//       [1024,1056) W -> Wh/Wl fp16 hi/lo split
// ---------------------------------------------------------------------------
__global__ __launch_bounds__(256, 4)
void prep_kernel(const float* __restrict__ Fi, const float* __restrict__ W,
                 _Float16* __restrict__ FiH, _Float16* __restrict__ FiT,
                 _Float16* __restrict__ Wh, _Float16* __restrict__ Wl)
{
    const int bid = blockIdx.x;
    const int t = threadIdx.x;

    if (bid >= 1024) {                      // W split
        const size_t base = (size_t)(bid - 1024) * 2048 + t * 8;
        half8 h, l;
        cvt8h_split(W + base, h, l);
        *(half8*)(Wh + base) = h;
        *(half8*)(Wl + base) = l;
        return;
    }

    __shared__ __align__(16) unsigned short tile[64][72];
    const int b  = bid >> 7;
    const int mt = (bid >> 2) & 31;
    const int dt = bid & 3;
    {
        const int i = t >> 2, jc = (t & 3) * 16;
        const float* src = Fi + ((size_t)b * Mm + mt * 64 + i) * Dd + dt * 64 + jc;
        union { half8 v; uint4 u; } p0, p1;
        p0.v = cvt8h(src);
        p1.v = cvt8h(src + 8);
        *(uint4*)&tile[i][jc]     = p0.u;
        *(uint4*)&tile[i][jc + 8] = p1.u;
        unsigned short* dh = reinterpret_cast<unsigned short*>(FiH)
            + ((size_t)b * Mm + mt * 64 + i) * Dd + dt * 64 + jc;
        *(uint4*)dh       = p0.u;
        *(uint4*)(dh + 8) = p1.u;
    }
    __syncthreads();
    {
        const int d = t >> 2, mc = (t & 3) * 16;
        unsigned short* dst = reinterpret_cast<unsigned short*>(FiT)
            + ((size_t)b * Dd + dt * 64 + d) * Mm + mt * 64 + mc;
        union { uint4 v[2]; unsigned short s[16]; } u;
#pragma unroll
        for (int s = 0; s < 16; ++s) u.s[s] = tile[mc + s][d];
        *(uint4*)dst       = u.v[0];
        *(uint4*)(dst + 8) = u.v[1];
    }
}

// ---------------------------------------------------------------------------
// qproj: q = fp16( x @ W^T + b ), 3-term fp16-split MFMA, W slab LDS-staged
// via coalesced global_load_lds (fixes the 64-line B-frag gathers).
// grid 512 x 256 thr: block = 32 rows; wave w owns output cols [w*64, w*64+64).
// K-loop: 8 iters of BK=32, single-buffer 2-barrier.
// ---------------------------------------------------------------------------
__global__ __launch_bounds__(256, 2)
void qproj_kernel(const float* __restrict__ x, const _Float16* __restrict__ Wh,
                  const _Float16* __restrict__ Wl, const float* __restrict__ bias,
                  _Float16* __restrict__ q)
{
    __shared__ __align__(16) _Float16 sWh[256 * 32];   // [e][k-chunk], chunk^= e&3
    __shared__ __align__(16) _Float16 sWl[256 * 32];

    const int tid = threadIdx.x;
    const int lane = tid & 63, w = tid >> 6;
    const int lo = lane & 15, hi = lane >> 4;
    const long r0 = (long)blockIdx.x * 32;

    floatx4 acc[2][4];
#pragma unroll
    for (int rt = 0; rt < 2; ++rt)
#pragma unroll
        for (int j = 0; j < 4; ++j) acc[rt][j] = (floatx4)0.0f;

    // DMA lane decomposition: 16 rows x 4 chunks per instr
    const int se = lane >> 2, sc = lane & 3;

    for (int k0 = 0; k0 < 256; k0 += 32) {
        __syncthreads();                    // all waves done reading previous slab
#pragma unroll
        for (int j = 0; j < 4; ++j) {
            const int e0 = (w * 4 + j) * 16;
            const int e = e0 + se;
            const int gc = sc ^ (e & 3);
            async16(Wh + (size_t)e * Dd + k0 + gc * 8, sWh + e0 * 32);
            async16(Wl + (size_t)e * Dd + k0 + gc * 8, sWl + e0 * 32);
        }
        __syncthreads();                    // DMA drained: slab in LDS

        half8 ah[2], al[2];
#pragma unroll
        for (int rt = 0; rt < 2; ++rt)
            cvt8h_split(x + (size_t)(r0 + rt * 16 + lo) * Dd + k0 + hi * 8, ah[rt], al[rt]);
#pragma unroll
        for (int jj = 0; jj < 4; ++jj) {
            const int e = (w * 4 + jj) * 16 + lo;
            half8 bh = *reinterpret_cast<const half8*>(&sWh[(e & 255) * 32 + ((hi ^ (e & 3)) * 8)]);
            half8 bl = *reinterpret_cast<const half8*>(&sWl[(e & 255) * 32 + ((hi ^ (e & 3)) * 8)]);
#pragma unroll
            for (int rt = 0; rt < 2; ++rt) {
                acc[rt][jj] = MFMA16H(ah[rt], bh, acc[rt][jj]);
                acc[rt][jj] = MFMA16H(ah[rt], bl, acc[rt][jj]);
                acc[rt][jj] = MFMA16H(al[rt], bh, acc[rt][jj]);
            }
        }
    }
#pragma unroll
    for (int jj = 0; jj < 4; ++jj) {
        const int e = (w * 4 + jj) * 16 + lo;
        const float bv = bias[e];
#pragma unroll
        for (int rt = 0; rt < 2; ++rt)
#pragma unroll
            for (int r = 0; r < 4; ++r)
                q[(size_t)(r0 + rt * 16 + hi * 4 + r) * Dd + e] = (_Float16)(acc[rt][jj][r] + bv);
    }
}

// ---------------------------------------------------------------------------
// flash: grid 512 = 8b x 16nt x 4kh, 256 thr (4 waves x 32 rows).
// Double-buffered (static A/B arrays). sFi staged KEY-PERMUTED (LDS row r
// holds key 2*(r&15)+(r>>4)) so P is written as packed ds_write_b32 pairs.
// sP pitch 40 halves -> 16B-aligned b128 PV reads.
// ---------------------------------------------------------------------------
__global__ __launch_bounds__(256, 2)
void flash_kernel(const _Float16* __restrict__ q, const _Float16* __restrict__ FiH,
                  const _Float16* __restrict__ FiT, _Float16* __restrict__ o_part,
                  float* __restrict__ m_part, float* __restrict__ l_part)
{
    __shared__ __align__(16) _Float16 sFiA[32 * 256];    // [key'][d], chunk-XOR (r&7)
    __shared__ __align__(16) _Float16 sFiB[32 * 256];
    __shared__ __align__(16) _Float16 sFiTA[256 * 32];   // [d][key], chunk-XOR (r&3)
    __shared__ __align__(16) _Float16 sFiTB[256 * 32];
    __shared__ __align__(16) _Float16 sP[4][32 * 40];    // per-wave P, pitch 40

    const int bid = blockIdx.x;
    const int b  = bid & 7;
    const int u  = bid >> 3;
    const int nt = u & 15;
    const int kh = u >> 4;
    const int tid = threadIdx.x;
    const int lane = tid & 63, w = tid >> 6;
    const int lo = lane & 15, hi = lane >> 4;
    const int nbase = nt * 128 + w * 32;

    const _Float16* fH = FiH + (size_t)b * Mm * Dd;
    const _Float16* fT = FiT + (size_t)b * Dd * Mm;

    // Q fragments (A layout: A[m=lo][k=hi*8+j])
    half8 qf[2][8];
    const _Float16* qb = q + ((size_t)b * Nn + nbase + lo) * Dd + hi * 8;
#pragma unroll
    for (int rt = 0; rt < 2; ++rt)
#pragma unroll
        for (int kk = 0; kk < 8; ++kk)
            qf[rt][kk] = *reinterpret_cast<const half8*>(qb + rt * 16 * Dd + kk * 32);

    half8 ones;
#pragma unroll
    for (int i = 0; i < 8; ++i) ones[i] = (_Float16)1.0f;

    floatx4 o[2][16];
    floatx4 ol[2];
#pragma unroll
    for (int rt = 0; rt < 2; ++rt) {
#pragma unroll
        for (int t = 0; t < 16; ++t) o[rt][t] = (floatx4)0.0f;
        ol[rt] = (floatx4)0.0f;
    }
    float m_i[2][4];
#pragma unroll
    for (int rt = 0; rt < 2; ++rt)
#pragma unroll
        for (int r = 0; r < 4; ++r) m_i[rt][r] = -INFINITY;

    // DMA issue only — no LDS reads here.
    auto stage = [&](int it, _Float16* dFi, _Float16* dFiT) {
        const int key0 = kh * 512 + it * 32;
#pragma unroll
        for (int j = 0; j < 4; ++j) {
            const int rbase = (w * 4 + j) * 2;
            const int r = rbase + (lane >> 5);          // LDS row
            const int kp = 2 * (r & 15) + (r >> 4);     // permuted global key
            const int gc = (lane & 31) ^ (r & 7);
            async16(fH + (size_t)(key0 + kp) * Dd + gc * 8, dFi + rbase * 256);
        }
#pragma unroll
        for (int j = 0; j < 4; ++j) {
            const int rbase = (w + j * 4) * 16;
            const int r = rbase + (lane >> 2);
            const int gc = (lane & 3) ^ (r & 3);
            async16(fT + (size_t)r * Mm + key0 + gc * 8, dFiT + rbase * 32);
        }
    };

    auto compute = [&](const _Float16* SFI, const _Float16* SFIT) {
        // ---- S = q . Fi^T : st=0 -> keys 2*lo, st=1 -> keys 2*lo+1 (permuted)
        floatx4 s[2][2];
#pragma unroll
        for (int rt = 0; rt < 2; ++rt)
#pragma unroll
            for (int st = 0; st < 2; ++st) s[rt][st] = (floatx4)0.0f;
#pragma unroll
        for (int st = 0; st < 2; ++st) {
            const int row = st * 16 + lo;
#pragma unroll
            for (int kk = 0; kk < 8; ++kk) {
                half8 bv = *reinterpret_cast<const half8*>(
                    SFI + row * 256 + (((kk * 4 + hi) ^ (lo & 7)) * 8));
                s[0][st] = MFMA16H(qf[0][kk], bv, s[0][st]);
                s[1][st] = MFMA16H(qf[1][kk], bv, s[1][st]);
            }
        }

        // ---- online max (C layout: col=lo, row=hi*4+r); conditional rescale
        float mn[2][4];
        bool chg = false;
#pragma unroll
        for (int rt = 0; rt < 2; ++rt)
#pragma unroll
            for (int r = 0; r < 4; ++r) {
                float mc = fmaxf(s[rt][0][r], s[rt][1][r]);
                mc = fmaxf(mc, __shfl_xor(mc, 1));
                mc = fmaxf(mc, __shfl_xor(mc, 2));
                mc = fmaxf(mc, __shfl_xor(mc, 4));
                mc = fmaxf(mc, __shfl_xor(mc, 8));
                mn[rt][r] = fmaxf(m_i[rt][r], mc);
                chg = chg || (mn[rt][r] > m_i[rt][r]);
            }
        if (__any(chg)) {
#pragma unroll
            for (int rt = 0; rt < 2; ++rt) {
                float al4[4];
#pragma unroll
                for (int r = 0; r < 4; ++r) {
                    al4[r] = __expf(m_i[rt][r] - mn[rt][r]);
                    m_i[rt][r] = mn[rt][r];
                }
#pragma unroll
                for (int t = 0; t < 16; ++t) {
                    floatx4 ot = o[rt][t];
#pragma unroll
                    for (int r = 0; r < 4; ++r) ot[r] *= al4[r];
                    o[rt][t] = ot;
                }
#pragma unroll
                for (int r = 0; r < 4; ++r) ol[rt][r] *= al4[r];
            }
        }
        // ---- p (fp16, round-first) -> sP packed b32: keys (2lo, 2lo+1) adjacent
#pragma unroll
        for (int rt = 0; rt < 2; ++rt)
#pragma unroll
            for (int r = 0; r < 4; ++r) {
                union { _Float16 h[2]; unsigned u; } pk;
                pk.h[0] = (_Float16)__expf(s[rt][0][r] - m_i[rt][r]);
                pk.h[1] = (_Float16)__expf(s[rt][1][r] - m_i[rt][r]);
                *reinterpret_cast<unsigned*>(
                    &sP[w][(rt * 16 + hi * 4 + r) * 40 + 2 * lo]) = pk.u;
            }

        // ---- O += P @ Fi (K=32); l via all-ones B-frag
        half8 pa0 = *reinterpret_cast<const half8*>(&sP[w][lo * 40 + hi * 8]);
        half8 pa1 = *reinterpret_cast<const half8*>(&sP[w][(16 + lo) * 40 + hi * 8]);
#pragma unroll
        for (int t = 0; t < 16; ++t) {
            half8 bv = *reinterpret_cast<const half8*>(
                SFIT + (t * 16 + lo) * 32 + ((hi ^ (lo & 3)) * 8));
            o[0][t] = MFMA16H(pa0, bv, o[0][t]);
            o[1][t] = MFMA16H(pa1, bv, o[1][t]);
        }
        ol[0] = MFMA16H(pa0, ones, ol[0]);
        ol[1] = MFMA16H(pa1, ones, ol[1]);
    };

    stage(0, sFiA, sFiTA);
    for (int it = 0; it < 16; it += 2) {
        __syncthreads();                        // drain A(it); all waves done with B
        stage(it + 1, sFiB, sFiTB);             // prefetch B during compute A
        compute(sFiA, sFiTA);
        __syncthreads();                        // drain B(it+1); all waves done with A
        if (it + 2 < 16) stage(it + 2, sFiA, sFiTA);
        compute(sFiB, sFiTB);
    }

    // ---- epilogue: fp16 o-partials + fp32 m/l partials (merge normalizes)
#pragma unroll
    for (int rt = 0; rt < 2; ++rt)
#pragma unroll
        for (int r = 0; r < 4; ++r) {
            const long gq = (long)b * Nn + nbase + rt * 16 + hi * 4 + r;
            const size_t obase = ((size_t)kh * (Bb * Nn) + gq) * Dd;
#pragma unroll
            for (int t = 0; t < 16; ++t)
                o_part[obase + t * 16 + lo] = (_Float16)o[rt][t][r];
            if (lo == 0) {
                m_part[(size_t)kh * (Bb * Nn) + gq] = m_i[rt][r];
                l_part[(size_t)kh * (Bb * Nn) + gq] = ol[rt][r];
            }
        }
}

// ---------------------------------------------------------------------------
// merge: combine 4 KV-split partials. grid 16384 x 256 thr (1 row / block).
// ---------------------------------------------------------------------------
__global__ __launch_bounds__(256, 8)
void merge_kernel(const _Float16* __restrict__ o_part, const float* __restrict__ m_part,
                  const float* __restrict__ l_part, float* __restrict__ out)
{
    const int row = blockIdx.x;
    const int col = threadIdx.x;
    float m[4], l[4];
#pragma unroll
    for (int k = 0; k < 4; ++k) {
        m[k] = m_part[(size_t)k * (Bb * Nn) + row];
        l[k] = l_part[(size_t)k * (Bb * Nn) + row];
    }
    float M = fmaxf(fmaxf(m[0], m[1]), fmaxf(m[2], m[3]));
    float denom = 0.f, acc = 0.f;
#pragma unroll
    for (int k = 0; k < 4; ++k) {
        const float wk = __expf(m[k] - M);
        denom += wk * l[k];
        acc += wk * (float)o_part[((size_t)k * (Bb * Nn) + row) * Dd + col];
    }
    out[(size_t)row * Dd + col] = acc / denom;
}

// ---------------------------------------------------------------------------
extern "C" void kernel_launch(void* const* d_in, const int* in_sizes, int n_in,
                              void* d_out, int out_size, void* d_ws, size_t ws_size,
                              hipStream_t stream)
{
    const float* x    = (const float*)d_in[0];
    const float* Fi   = (const float*)d_in[1];
    const float* W    = (const float*)d_in[2];
    const float* bias = (const float*)d_in[3];
    float* out = (float*)d_out;

    _Float16* q_ws = (_Float16*)d_ws;                                // 8.4 MB
    _Float16* FiH  = q_ws + (size_t)Bb * Nn * Dd;                    // 8.4 MB
    _Float16* FiT  = FiH + (size_t)Bb * Mm * Dd;                     // 8.4 MB
    _Float16* Wh   = FiT + (size_t)Bb * Dd * Mm;                     // 128 KB
    _Float16* Wl   = Wh + (size_t)Dd * Dd;                           // 128 KB
    _Float16* o_part = Wl + (size_t)Dd * Dd;                         // 33.6 MB
    float* m_part  = (float*)(o_part + (size_t)4 * Bb * Nn * Dd);    // 256 KB
    float* l_part  = m_part + (size_t)4 * Bb * Nn;                   // 256 KB

    hipLaunchKernelGGL(prep_kernel, dim3(1056), dim3(256), 0, stream, Fi, W, FiH, FiT, Wh, Wl);
    hipLaunchKernelGGL(qproj_kernel, dim3(512), dim3(256), 0, stream, x, Wh, Wl, bias, q_ws);
    hipLaunchKernelGGL(flash_kernel, dim3(512), dim3(256), 0, stream, q_ws, FiH, FiT,
                       o_part, m_part, l_part);
    hipLaunchKernelGGL(merge_kernel, dim3(16384), dim3(256), 0, stream, o_part, m_part, l_part, out);
}

// Round 9
// 211.990 us; speedup vs baseline: 1.4852x; 1.0224x over previous
//
#include <hip/hip_runtime.h>
#include <hip/hip_bf16.h>

typedef _Float16 half8 __attribute__((ext_vector_type(8)));
typedef float floatx4 __attribute__((ext_vector_type(4)));

#define MFMA16H(a, b, c) __builtin_amdgcn_mfma_f32_16x16x32_f16((a), (b), (c), 0, 0, 0)

static constexpr int Bb = 8, Nn = 2048, Mm = 2048, Dd = 256;

// async global->LDS DMA, 16B/lane. LDS dest = wave-uniform base + lane*16.
__device__ inline void async16(const void* g, void* l)
{
    __builtin_amdgcn_global_load_lds((const __attribute__((address_space(1))) unsigned int*)g,
                                     (__attribute__((address_space(3))) unsigned int*)l,
                                     16, 0, 0);
}

__device__ inline half8 cvt8h(const float* __restrict__ p)
{
    float4 f0 = *reinterpret_cast<const float4*>(p);
    float4 f1 = *reinterpret_cast<const float4*>(p + 4);
    half8 r;
    r[0] = (_Float16)f0.x; r[1] = (_Float16)f0.y; r[2] = (_Float16)f0.z; r[3] = (_Float16)f0.w;
    r[4] = (_Float16)f1.x; r[5] = (_Float16)f1.y; r[6] = (_Float16)f1.z; r[7] = (_Float16)f1.w;
    return r;
}

__device__ inline void cvt8h_split(const float* __restrict__ p, half8& h, half8& l)
{
    float4 f0 = *reinterpret_cast<const float4*>(p);
    float4 f1 = *reinterpret_cast<const float4*>(p + 4);
    float f[8] = {f0.x, f0.y, f0.z, f0.w, f1.x, f1.y, f1.z, f1.w};
#pragma unroll
    for (int i = 0; i < 8; ++i) {
        _Float16 hh = (_Float16)f[i];
        h[i] = hh;
        l[i] = (_Float16)(f[i] - (float)hh);
    }
}

// ---------------------------------------------------------------------------
// prep: [0,1024)   Fi -> FiH fp16 + FiT fp16 transpose (XOR-swizzled LDS tile,
//                  conflict-free: chunk ^= row>>4 keys the 4 mc-groups apart)
//       [1024,1056) W -> Wh/Wl fp16 hi/lo split
// ---------------------------------------------------------------------------
__global__ __launch_bounds__(256, 4)
void prep_kernel(const float* __restrict__ Fi, const float* __restrict__ W,
                 _Float16* __restrict__ FiH, _Float16* __restrict__ FiT,
                 _Float16* __restrict__ Wh, _Float16* __restrict__ Wl)
{
    const int bid = blockIdx.x;
    const int t = threadIdx.x;

    if (bid >= 1024) {                      // W split
        const size_t base = (size_t)(bid - 1024) * 2048 + t * 8;
        half8 h, l;
        cvt8h_split(W + base, h, l);
        *(half8*)(Wh + base) = h;
        *(half8*)(Wl + base) = l;
        return;
    }

    // logical tile[i][j] stored at [i][ (j&15) + 16*((j>>4)^(i>>4)) ]
    __shared__ __align__(16) unsigned short tile[64][64];
    const int b  = bid >> 7;
    const int mt = (bid >> 2) & 31;
    const int dt = bid & 3;
    {
        const int i = t >> 2, jc = (t & 3) * 16;
        const int pc = ((jc >> 4) ^ (i >> 4)) * 16;
        const float* src = Fi + ((size_t)b * Mm + mt * 64 + i) * Dd + dt * 64 + jc;
        union { half8 v; uint4 u; } p0, p1;
        p0.v = cvt8h(src);
        p1.v = cvt8h(src + 8);
        *(uint4*)&tile[i][pc]     = p0.u;
        *(uint4*)&tile[i][pc + 8] = p1.u;
        unsigned short* dh = reinterpret_cast<unsigned short*>(FiH)
            + ((size_t)b * Mm + mt * 64 + i) * Dd + dt * 64 + jc;
        *(uint4*)dh       = p0.u;
        *(uint4*)(dh + 8) = p1.u;
    }
    __syncthreads();
    {
        const int d = t >> 2, mc = (t & 3) * 16;
        unsigned short* dst = reinterpret_cast<unsigned short*>(FiT)
            + ((size_t)b * Dd + dt * 64 + d) * Mm + mt * 64 + mc;
        union { uint4 v[2]; unsigned short s[16]; } u;
#pragma unroll
        for (int s = 0; s < 16; ++s) {
            const int row = mc + s;
            u.s[s] = tile[row][((d >> 4) ^ (row >> 4)) * 16 + (d & 15)];
        }
        *(uint4*)dst       = u.v[0];
        *(uint4*)(dst + 8) = u.v[1];
    }
}

// ---------------------------------------------------------------------------
// qproj: q = fp16( x @ W^T + b ), 3-term fp16-split MFMA, W slabs LDS-staged
// via global_load_lds, DOUBLE-BUFFERED (static A/B arrays).
// grid 512 x 256 thr: block = 32 rows; wave w owns output cols [w*64, w*64+64).
// ---------------------------------------------------------------------------
__global__ __launch_bounds__(256, 2)
void qproj_kernel(const float* __restrict__ x, const _Float16* __restrict__ Wh,
                  const _Float16* __restrict__ Wl, const float* __restrict__ bias,
                  _Float16* __restrict__ q)
{
    __shared__ __align__(16) _Float16 sWhA[256 * 32];   // [e][k-chunk], chunk ^= e&3
    __shared__ __align__(16) _Float16 sWlA[256 * 32];
    __shared__ __align__(16) _Float16 sWhB[256 * 32];
    __shared__ __align__(16) _Float16 sWlB[256 * 32];

    const int tid = threadIdx.x;
    const int lane = tid & 63, w = tid >> 6;
    const int lo = lane & 15, hi = lane >> 4;
    const long r0 = (long)blockIdx.x * 32;

    floatx4 acc[2][4];
#pragma unroll
    for (int rt = 0; rt < 2; ++rt)
#pragma unroll
        for (int j = 0; j < 4; ++j) acc[rt][j] = (floatx4)0.0f;

    const int se = lane >> 2, sc = lane & 3;   // 16 rows x 4 chunks per instr

    auto stage = [&](int k0, _Float16* dWh, _Float16* dWl) {
#pragma unroll
        for (int j = 0; j < 4; ++j) {
            const int e0 = (w * 4 + j) * 16;
            const int e = e0 + se;
            const int gc = sc ^ (e & 3);
            async16(Wh + (size_t)e * Dd + k0 + gc * 8, dWh + e0 * 32);
            async16(Wl + (size_t)e * Dd + k0 + gc * 8, dWl + e0 * 32);
        }
    };

    auto compute = [&](int k0, const _Float16* SWh, const _Float16* SWl) {
        half8 ah[2], al[2];
#pragma unroll
        for (int rt = 0; rt < 2; ++rt)
            cvt8h_split(x + (size_t)(r0 + rt * 16 + lo) * Dd + k0 + hi * 8, ah[rt], al[rt]);
#pragma unroll
        for (int jj = 0; jj < 4; ++jj) {
            const int e = (w * 4 + jj) * 16 + lo;
            half8 bh = *reinterpret_cast<const half8*>(&SWh[(e & 255) * 32 + ((hi ^ (e & 3)) * 8)]);
            half8 bl = *reinterpret_cast<const half8*>(&SWl[(e & 255) * 32 + ((hi ^ (e & 3)) * 8)]);
#pragma unroll
            for (int rt = 0; rt < 2; ++rt) {
                acc[rt][jj] = MFMA16H(ah[rt], bh, acc[rt][jj]);
                acc[rt][jj] = MFMA16H(ah[rt], bl, acc[rt][jj]);
                acc[rt][jj] = MFMA16H(al[rt], bh, acc[rt][jj]);
            }
        }
    };

    stage(0, sWhA, sWlA);
    for (int k0 = 0; k0 < 256; k0 += 64) {
        __syncthreads();                       // drain A; all done reading B
        stage(k0 + 32, sWhB, sWlB);
        compute(k0, sWhA, sWlA);
        __syncthreads();                       // drain B; all done reading A
        if (k0 + 64 < 256) stage(k0 + 64, sWhA, sWlA);
        compute(k0 + 32, sWhB, sWlB);
    }
#pragma unroll
    for (int jj = 0; jj < 4; ++jj) {
        const int e = (w * 4 + jj) * 16 + lo;
        const float bv = bias[e];
#pragma unroll
        for (int rt = 0; rt < 2; ++rt)
#pragma unroll
            for (int r = 0; r < 4; ++r)
                q[(size_t)(r0 + rt * 16 + hi * 4 + r) * Dd + e] = (_Float16)(acc[rt][jj][r] + bv);
    }
}

// ---------------------------------------------------------------------------
// flash: grid 512 = 8b x 16nt x 4kh, 256 thr (4 waves x 32 rows). R7 body:
// double-buffered static LDS A/B, unpermuted keys, sP pitch 36.
// l computed by PV MFMA against a constant all-ones B fragment.
// ---------------------------------------------------------------------------
__global__ __launch_bounds__(256, 2)
void flash_kernel(const _Float16* __restrict__ q, const _Float16* __restrict__ FiH,
                  const _Float16* __restrict__ FiT, _Float16* __restrict__ o_part,
                  float* __restrict__ m_part, float* __restrict__ l_part)
{
    __shared__ __align__(16) _Float16 sFiA[32 * 256];    // [key][d], chunk-XOR (r&7)
    __shared__ __align__(16) _Float16 sFiB[32 * 256];
    __shared__ __align__(16) _Float16 sFiTA[256 * 32];   // [d][key], chunk-XOR (r&3)
    __shared__ __align__(16) _Float16 sFiTB[256 * 32];
    __shared__ __align__(16) _Float16 sP[4][32 * 36];    // per-wave P, pitch 36

    const int bid = blockIdx.x;
    const int b  = bid & 7;
    const int u  = bid >> 3;
    const int nt = u & 15;
    const int kh = u >> 4;
    const int tid = threadIdx.x;
    const int lane = tid & 63, w = tid >> 6;
    const int lo = lane & 15, hi = lane >> 4;
    const int nbase = nt * 128 + w * 32;

    const _Float16* fH = FiH + (size_t)b * Mm * Dd;
    const _Float16* fT = FiT + (size_t)b * Dd * Mm;

    // Q fragments (A layout: A[m=lo][k=hi*8+j])
    half8 qf[2][8];
    const _Float16* qb = q + ((size_t)b * Nn + nbase + lo) * Dd + hi * 8;
#pragma unroll
    for (int rt = 0; rt < 2; ++rt)
#pragma unroll
        for (int kk = 0; kk < 8; ++kk)
            qf[rt][kk] = *reinterpret_cast<const half8*>(qb + rt * 16 * Dd + kk * 32);

    half8 ones;
#pragma unroll
    for (int i = 0; i < 8; ++i) ones[i] = (_Float16)1.0f;

    floatx4 o[2][16];
    floatx4 ol[2];
#pragma unroll
    for (int rt = 0; rt < 2; ++rt) {
#pragma unroll
        for (int t = 0; t < 16; ++t) o[rt][t] = (floatx4)0.0f;
        ol[rt] = (floatx4)0.0f;
    }
    float m_i[2][4];
#pragma unroll
    for (int rt = 0; rt < 2; ++rt)
#pragma unroll
        for (int r = 0; r < 4; ++r) m_i[rt][r] = -INFINITY;

    auto stage = [&](int it, _Float16* dFi, _Float16* dFiT) {
        const int key0 = kh * 512 + it * 32;
#pragma unroll
        for (int j = 0; j < 4; ++j) {
            const int rbase = (w * 4 + j) * 2;
            const int r = rbase + (lane >> 5);
            const int gc = (lane & 31) ^ (r & 7);
            async16(fH + (size_t)(key0 + r) * Dd + gc * 8, dFi + rbase * 256);
        }
#pragma unroll
        for (int j = 0; j < 4; ++j) {
            const int rbase = (w + j * 4) * 16;
            const int r = rbase + (lane >> 2);
            const int gc = (lane & 3) ^ (r & 3);
            async16(fT + (size_t)r * Mm + key0 + gc * 8, dFiT + rbase * 32);
        }
    };

    auto compute = [&](const _Float16* SFI, const _Float16* SFIT) {
        floatx4 s[2][2];
#pragma unroll
        for (int rt = 0; rt < 2; ++rt)
#pragma unroll
            for (int st = 0; st < 2; ++st) s[rt][st] = (floatx4)0.0f;
#pragma unroll
        for (int st = 0; st < 2; ++st) {
            const int row = st * 16 + lo;
#pragma unroll
            for (int kk = 0; kk < 8; ++kk) {
                half8 bv = *reinterpret_cast<const half8*>(
                    SFI + row * 256 + (((kk * 4 + hi) ^ (lo & 7)) * 8));
                s[0][st] = MFMA16H(qf[0][kk], bv, s[0][st]);
                s[1][st] = MFMA16H(qf[1][kk], bv, s[1][st]);
            }
        }

        float mn[2][4];
        bool chg = false;
#pragma unroll
        for (int rt = 0; rt < 2; ++rt)
#pragma unroll
            for (int r = 0; r < 4; ++r) {
                float mc = fmaxf(s[rt][0][r], s[rt][1][r]);
                mc = fmaxf(mc, __shfl_xor(mc, 1));
                mc = fmaxf(mc, __shfl_xor(mc, 2));
                mc = fmaxf(mc, __shfl_xor(mc, 4));
                mc = fmaxf(mc, __shfl_xor(mc, 8));
                mn[rt][r] = fmaxf(m_i[rt][r], mc);
                chg = chg || (mn[rt][r] > m_i[rt][r]);
            }
        if (__any(chg)) {
#pragma unroll
            for (int rt = 0; rt < 2; ++rt) {
                float al4[4];
#pragma unroll
                for (int r = 0; r < 4; ++r) {
                    al4[r] = __expf(m_i[rt][r] - mn[rt][r]);
                    m_i[rt][r] = mn[rt][r];
                }
#pragma unroll
                for (int t = 0; t < 16; ++t) {
                    floatx4 ot = o[rt][t];
#pragma unroll
                    for (int r = 0; r < 4; ++r) ot[r] *= al4[r];
                    o[rt][t] = ot;
                }
#pragma unroll
                for (int r = 0; r < 4; ++r) ol[rt][r] *= al4[r];
            }
        }
#pragma unroll
        for (int rt = 0; rt < 2; ++rt)
#pragma unroll
            for (int r = 0; r < 4; ++r) {
                _Float16 p0 = (_Float16)__expf(s[rt][0][r] - m_i[rt][r]);
                _Float16 p1 = (_Float16)__expf(s[rt][1][r] - m_i[rt][r]);
                sP[w][(rt * 16 + hi * 4 + r) * 36 + lo]      = p0;
                sP[w][(rt * 16 + hi * 4 + r) * 36 + 16 + lo] = p1;
            }

        half8 pa0 = *reinterpret_cast<const half8*>(&sP[w][lo * 36 + hi * 8]);
        half8 pa1 = *reinterpret_cast<const half8*>(&sP[w][(16 + lo) * 36 + hi * 8]);
#pragma unroll
        for (int t = 0; t < 16; ++t) {
            half8 bv = *reinterpret_cast<const half8*>(
                SFIT + (t * 16 + lo) * 32 + ((hi ^ (lo & 3)) * 8));
            o[0][t] = MFMA16H(pa0, bv, o[0][t]);
            o[1][t] = MFMA16H(pa1, bv, o[1][t]);
        }
        ol[0] = MFMA16H(pa0, ones, ol[0]);
        ol[1] = MFMA16H(pa1, ones, ol[1]);
    };

    stage(0, sFiA, sFiTA);
    for (int it = 0; it < 16; it += 2) {
        __syncthreads();                        // drain A(it); all waves done with B
        stage(it + 1, sFiB, sFiTB);             // prefetch B during compute A
        compute(sFiA, sFiTA);
        __syncthreads();                        // drain B(it+1); all waves done with A
        if (it + 2 < 16) stage(it + 2, sFiA, sFiTA);
        compute(sFiB, sFiTB);
    }

    // ---- epilogue: fp16 o-partials + fp32 m/l partials (merge normalizes)
#pragma unroll
    for (int rt = 0; rt < 2; ++rt)
#pragma unroll
        for (int r = 0; r < 4; ++r) {
            const long gq = (long)b * Nn + nbase + rt * 16 + hi * 4 + r;
            const size_t obase = ((size_t)kh * (Bb * Nn) + gq) * Dd;
#pragma unroll
            for (int t = 0; t < 16; ++t)
                o_part[obase + t * 16 + lo] = (_Float16)o[rt][t][r];
            if (lo == 0) {
                m_part[(size_t)kh * (Bb * Nn) + gq] = m_i[rt][r];
                l_part[(size_t)kh * (Bb * Nn) + gq] = ol[rt][r];
            }
        }
}

// ---------------------------------------------------------------------------
// merge: combine 4 KV-split partials. grid 2048 x 256 thr, 8 rows/block.
// ---------------------------------------------------------------------------
__global__ __launch_bounds__(256, 8)
void merge_kernel(const _Float16* __restrict__ o_part, const float* __restrict__ m_part,
                  const float* __restrict__ l_part, float* __restrict__ out)
{
    const int col = threadIdx.x;
#pragma unroll
    for (int rr = 0; rr < 8; ++rr) {
        const int row = blockIdx.x * 8 + rr;
        float m[4], l[4];
#pragma unroll
        for (int k = 0; k < 4; ++k) {
            m[k] = m_part[(size_t)k * (Bb * Nn) + row];
            l[k] = l_part[(size_t)k * (Bb * Nn) + row];
        }
        float M = fmaxf(fmaxf(m[0], m[1]), fmaxf(m[2], m[3]));
        float denom = 0.f, acc = 0.f;
#pragma unroll
        for (int k = 0; k < 4; ++k) {
            const float wk = __expf(m[k] - M);
            denom += wk * l[k];
            acc += wk * (float)o_part[((size_t)k * (Bb * Nn) + row) * Dd + col];
        }
        out[(size_t)row * Dd + col] = acc / denom;
    }
}

// ---------------------------------------------------------------------------
extern "C" void kernel_launch(void* const* d_in, const int* in_sizes, int n_in,
                              void* d_out, int out_size, void* d_ws, size_t ws_size,
                              hipStream_t stream)
{
    const float* x    = (const float*)d_in[0];
    const float* Fi   = (const float*)d_in[1];
    const float* W    = (const float*)d_in[2];
    const float* bias = (const float*)d_in[3];
    float* out = (float*)d_out;

    _Float16* q_ws = (_Float16*)d_ws;                                // 8.4 MB
    _Float16* FiH  = q_ws + (size_t)Bb * Nn * Dd;                    // 8.4 MB
    _Float16* FiT  = FiH + (size_t)Bb * Mm * Dd;                     // 8.4 MB
    _Float16* Wh   = FiT + (size_t)Bb * Dd * Mm;                     // 128 KB
    _Float16* Wl   = Wh + (size_t)Dd * Dd;                           // 128 KB
    _Float16* o_part = Wl + (size_t)Dd * Dd;                         // 33.6 MB
    float* m_part  = (float*)(o_part + (size_t)4 * Bb * Nn * Dd);    // 256 KB
    float* l_part  = m_part + (size_t)4 * Bb * Nn;                   // 256 KB

    hipLaunchKernelGGL(prep_kernel, dim3(1056), dim3(256), 0, stream, Fi, W, FiH, FiT, Wh, Wl);
    hipLaunchKernelGGL(qproj_kernel, dim3(512), dim3(256), 0, stream, x, Wh, Wl, bias, q_ws);
    hipLaunchKernelGGL(flash_kernel, dim3(512), dim3(256), 0, stream, q_ws, FiH, FiT,
                       o_part, m_part, l_part);
    hipLaunchKernelGGL(merge_kernel, dim3(2048), dim3(256), 0, stream, o_part, m_part, l_part, out);
}